// Round 12
// baseline (230.335 us; speedup 1.0000x reference)
//
#include <hip/hip_runtime.h>

typedef unsigned short u16;
typedef __attribute__((ext_vector_type(8))) short bf16x8;
typedef __attribute__((ext_vector_type(8))) unsigned short u16x8;
typedef __attribute__((ext_vector_type(4))) unsigned short u16x4;
typedef __attribute__((ext_vector_type(4))) unsigned u32x4;
typedef __attribute__((ext_vector_type(4))) float f32x4;

#define DEVI static __device__ __forceinline__

DEVI u16 f2b(float f) {
  unsigned u = __builtin_bit_cast(unsigned, f);
  return (u16)((u + 0x7FFFu + ((u >> 16) & 1u)) >> 16);
}

DEVI unsigned cvtpk(float a, float b) {  // lo16 = bf16(a), hi16 = bf16(b)
  unsigned r;
  asm("v_cvt_pk_bf16_f32 %0, %1, %2" : "=v"(r) : "v"(a), "v"(b));
  return r;
}

DEVI void gload_lds16(const void* g, void* l) {
  __builtin_amdgcn_global_load_lds(
      (const __attribute__((address_space(1))) unsigned int*)g,
      (__attribute__((address_space(3))) unsigned int*)l, 16, 0, 0);
}

// ---------------- prep kernels ----------------

// xb2[(b*128+w)][y][256] bf16: column-major panels so the fused kernel's x-slab
// reads are contiguous (each (b,w) column = 64 KB panel).
__global__ __launch_bounds__(256) void prep_x2(const float* __restrict__ x, u16* __restrict__ xb2) {
  const int n8 = 65536 * 256 / 8;
  int i = blockIdx.x * blockDim.x + threadIdx.x;
  for (; i < n8; i += gridDim.x * blockDim.x) {
    const float4* p = (const float4*)x + (size_t)i * 2;
    float4 a = p[0], b = p[1];
    u16x8 r;
    r[0] = f2b(a.x); r[1] = f2b(a.y); r[2] = f2b(a.z); r[3] = f2b(a.w);
    r[4] = f2b(b.x); r[5] = f2b(b.y); r[6] = f2b(b.z); r[7] = f2b(b.w);
    const int t = i >> 5, c0 = (i & 31) * 8;
    const int b_ = t >> 14, y = (t >> 7) & 127, w = t & 127;
    *(u16x8*)(xb2 + (((size_t)(b_ * 128 + w) * 128) + y) * 256 + c0) = r;
  }
}

// wqkvT[1536][256]: row n<512 -> Wq[:,n]*0.125 ; 512..1023 -> Wk ; 1024.. -> Wv
// woT[256][512]: row n -> Wo[:,n] ;  bqkv[1536] = concat(bq*0.125, bk, bv)
__global__ __launch_bounds__(256) void prep_w(
    const float* __restrict__ Wq, const float* __restrict__ Wk,
    const float* __restrict__ Wv, const float* __restrict__ Wo,
    const float* __restrict__ bq, const float* __restrict__ bk, const float* __restrict__ bv,
    u16* __restrict__ wqkvT, u16* __restrict__ woT, float* __restrict__ bqkv) {
  const int NW1 = 1536 * 256, NW2 = 256 * 512;
  const int total = NW1 + NW2 + 1536;
  int i = blockIdx.x * blockDim.x + threadIdx.x;
  for (; i < total; i += gridDim.x * blockDim.x) {
    if (i < NW1) {
      int nn = i >> 8, kk = i & 255;
      float v;
      if (nn < 512)       v = Wq[kk * 512 + nn] * 0.125f;
      else if (nn < 1024) v = Wk[kk * 512 + (nn - 512)];
      else                v = Wv[kk * 512 + (nn - 1024)];
      wqkvT[i] = f2b(v);
    } else if (i < NW1 + NW2) {
      int j = i - NW1;
      int nn = j >> 9, kk = j & 511;
      woT[j] = f2b(Wo[kk * 256 + nn]);
    } else {
      int j = i - NW1 - NW2;
      bqkv[j] = (j < 512) ? bq[j] * 0.125f : (j < 1024 ? bk[j - 512] : bv[j - 1024]);
    }
  }
}

// ---------------- fused QKV-projection + axial attention (v3: LDS-staged W) ----------------
// One block (4 waves) per (b,w,head). Round-11 diagnosis: per-lane scattered global
// W reads interleaved with MFMA = latency chains (MfmaUtil 14.7%, 190us). Fix = the
// proven gemm staging: per K-chunk (4 x 64), cooperatively global_load_lds the head's
// W-slab [192 rows (q|k|v) x 64] = 24 KB into a DOUBLE BUFFER (2x24 KB) that aliases
// the future qld/kld/vt region; counted vmcnt(6) keeps the next slab in flight across
// barriers. areg x-loads issued FIRST (oldest) so the first vmcnt(6) drains them.
// q/k/v accumulate in regs across chunks (96 VGPR) and are written to LDS only after
// the final barrier (wbuf dead). W LDS reads: chunk^(row&7) swizzle, 2-way, broadcast.
// Back end (QK^T/softmax/butterfly/PV/store) byte-identical to passing round 11.

__global__ __launch_bounds__(256) void qkv_attn(
    const u16* __restrict__ xb2, const u16* __restrict__ wqkvT,
    const float* __restrict__ bqkv, u16* __restrict__ ao) {
  __shared__ u16 smem[24576];    // 48 KB total
  u16* qld = smem;               // [128 y][64 dh] chunk^(y&7) swizzled   (after front end)
  u16* kld = smem + 8192;        // [128 y][64 dh] chunk^(y&7) swizzled
  u16* vt  = smem + 16384;       // [64 dh][128 y] chunk-swizzled (v5 layout)
  // front end: wbuf[kt&1] = smem + (kt&1)*12288, each 24 KB (aliases outputs)

  const int g = blockIdx.x;
  const int n = g & 7, ct = g >> 3;  // head, b*128+w
  const int tid = threadIdx.x, lane = tid & 63, wid = tid >> 6;
  const int hi = lane >> 4, lo = lane & 15;
  const int wr = wid >> 1, wc = wid & 1;  // gemm decomp: y rows wr*64, dh cols wc*32

  const u16* Xp = xb2 + (size_t)ct * 32768;  // [128][256]
  const int hb = n * 64;                     // head's row base within each W matrix

  // ---- x slab -> regs FIRST (oldest vmcnt entries; drained by first vmcnt(6)) ----
  bf16x8 areg[4][8];
#pragma unroll
  for (int yT = 0; yT < 4; ++yT)
#pragma unroll
    for (int ks = 0; ks < 8; ++ks)
      areg[yT][ks] = *(const bf16x8*)(Xp + (wr * 64 + yT * 16 + lo) * 256 + hi * 8 + ks * 32);

  // ---- cooperative W-slab staging: slab row sr = m*64 + r (m: 0=q,1=k,2=v) ----
  auto stageW = [&](int kt) {
    u16* dst = &smem[(kt & 1) * 12288];
    const int kc = kt * 64;
#pragma unroll
    for (int it = 0; it < 6; ++it) {
      const int c = it * 256 + tid;       // 0..1535 : 16B chunk index in slab
      const int sr = c >> 3, ch = c & 7;  // slab row 0..191, chunk 0..7
      const int grow = hb + ((sr >> 6) << 9) + (sr & 63);
      const int gcol = kc + ((ch ^ (sr & 7)) << 3);  // inverse-swizzled source
      gload_lds16(wqkvT + (size_t)grow * 256 + gcol, &dst[c * 8]);
    }
  };

  f32x4 aq[2][4], ak[2][4], av[4][2];
#pragma unroll
  for (int i2 = 0; i2 < 2; ++i2)
#pragma unroll
    for (int j4 = 0; j4 < 4; ++j4) {
      aq[i2][j4] = f32x4{0.f, 0.f, 0.f, 0.f};
      ak[i2][j4] = f32x4{0.f, 0.f, 0.f, 0.f};
      av[j4][i2] = f32x4{0.f, 0.f, 0.f, 0.f};
    }

  stageW(0);
#pragma unroll
  for (int kt = 0; kt < 4; ++kt) {
    if (kt < 3) {
      stageW(kt + 1);
      asm volatile("s_waitcnt vmcnt(6)" ::: "memory");  // slab kt ready; kt+1 in flight
    } else {
      asm volatile("s_waitcnt vmcnt(0)" ::: "memory");
    }
    __builtin_amdgcn_sched_barrier(0);
    __builtin_amdgcn_s_barrier();
    const u16* wb = &smem[(kt & 1) * 12288];
#pragma unroll
    for (int ks2 = 0; ks2 < 2; ++ks2) {
      const int cs = ((hi + ks2 * 4) ^ (lo & 7)) << 3;  // swizzled k-chunk
      // q: slab rows [0,64)
      {
        bf16x8 w0 = *(const bf16x8*)&wb[(wc * 32 + lo) * 64 + cs];
        bf16x8 w1 = *(const bf16x8*)&wb[(wc * 32 + 16 + lo) * 64 + cs];
#pragma unroll
        for (int yT = 0; yT < 4; ++yT) {
          aq[0][yT] = __builtin_amdgcn_mfma_f32_16x16x32_bf16(w0, areg[yT][2 * kt + ks2], aq[0][yT], 0, 0, 0);
          aq[1][yT] = __builtin_amdgcn_mfma_f32_16x16x32_bf16(w1, areg[yT][2 * kt + ks2], aq[1][yT], 0, 0, 0);
        }
      }
      // k: slab rows [64,128)
      {
        bf16x8 w0 = *(const bf16x8*)&wb[(64 + wc * 32 + lo) * 64 + cs];
        bf16x8 w1 = *(const bf16x8*)&wb[(64 + wc * 32 + 16 + lo) * 64 + cs];
#pragma unroll
        for (int yT = 0; yT < 4; ++yT) {
          ak[0][yT] = __builtin_amdgcn_mfma_f32_16x16x32_bf16(w0, areg[yT][2 * kt + ks2], ak[0][yT], 0, 0, 0);
          ak[1][yT] = __builtin_amdgcn_mfma_f32_16x16x32_bf16(w1, areg[yT][2 * kt + ks2], ak[1][yT], 0, 0, 0);
        }
      }
      // v: slab rows [128,192)  (untransposed: mfma(x, w))
      {
        bf16x8 w0 = *(const bf16x8*)&wb[(128 + wc * 32 + lo) * 64 + cs];
        bf16x8 w1 = *(const bf16x8*)&wb[(128 + wc * 32 + 16 + lo) * 64 + cs];
#pragma unroll
        for (int yT = 0; yT < 4; ++yT) {
          av[yT][0] = __builtin_amdgcn_mfma_f32_16x16x32_bf16(areg[yT][2 * kt + ks2], w0, av[yT][0], 0, 0, 0);
          av[yT][1] = __builtin_amdgcn_mfma_f32_16x16x32_bf16(areg[yT][2 * kt + ks2], w1, av[yT][1], 0, 0, 0);
        }
      }
    }
    __builtin_amdgcn_sched_barrier(0);
    __builtin_amdgcn_s_barrier();  // all reads of wb done; safe to restage/overwrite
  }

  // ---- write q/k/v from regs to LDS (wbuf dead after final barrier) ----
#pragma unroll
  for (int dhT = 0; dhT < 2; ++dhT) {
    const int dh0 = wc * 32 + dhT * 16 + hi * 4;
    float4 bq4 = *(const float4*)&bqkv[n * 64 + dh0];
#pragma unroll
    for (int yT = 0; yT < 4; ++yT) {
      const int y = wr * 64 + yT * 16 + lo;
      u16x4 pkq;
      pkq[0] = f2b(aq[dhT][yT][0] + bq4.x);
      pkq[1] = f2b(aq[dhT][yT][1] + bq4.y);
      pkq[2] = f2b(aq[dhT][yT][2] + bq4.z);
      pkq[3] = f2b(aq[dhT][yT][3] + bq4.w);
      *(u16x4*)&qld[y * 64 + (((dh0 >> 3) ^ (y & 7)) << 3) + (dh0 & 7)] = pkq;
      u16x4 pkk;
      pkk[0] = f2b(ak[dhT][yT][0]);
      pkk[1] = f2b(ak[dhT][yT][1]);
      pkk[2] = f2b(ak[dhT][yT][2]);
      pkk[3] = f2b(ak[dhT][yT][3]);
      *(u16x4*)&kld[y * 64 + (((dh0 >> 3) ^ (y & 7)) << 3) + (dh0 & 7)] = pkk;
    }
  }
#pragma unroll
  for (int dhT = 0; dhT < 2; ++dhT) {
    const int dh = wc * 32 + dhT * 16 + lo;
    const float bv = bqkv[1024 + n * 64 + dh];
#pragma unroll
    for (int yT = 0; yT < 4; ++yT) {
      const int y0 = wr * 64 + yT * 16 + hi * 4;
      const int cch = y0 >> 3;
      u16x4 pk;
      pk[0] = f2b(av[yT][dhT][0] + bv);
      pk[1] = f2b(av[yT][dhT][1] + bv);
      pk[2] = f2b(av[yT][dhT][2] + bv);
      pk[3] = f2b(av[yT][dhT][3] + bv);
      *(u16x4*)&vt[dh * 128 + (((cch & 8) | ((cch & 7) ^ (dh & 7))) << 3) + (y0 & 7)] = pk;
    }
  }

  __syncthreads();  // qld/kld/vt complete

  // ---- swapped QK^T: s2[cg][ni] = S^T fragments (round-11 verbatim) ----
  bf16x8 qf[2][2];
#pragma unroll
  for (int cg = 0; cg < 2; ++cg)
#pragma unroll
    for (int ks = 0; ks < 2; ++ks) {
      const int qr = wid * 32 + cg * 16 + lo;
      qf[cg][ks] = *(const bf16x8*)&qld[qr * 64 + (((hi + ks * 4) ^ (qr & 7)) << 3)];
    }
  f32x4 s2[2][8];
#pragma unroll
  for (int cg = 0; cg < 2; ++cg)
#pragma unroll
    for (int ni = 0; ni < 8; ++ni) s2[cg][ni] = f32x4{0.f, 0.f, 0.f, 0.f};
  __builtin_amdgcn_s_setprio(1);
#pragma unroll
  for (int ks = 0; ks < 2; ++ks)
#pragma unroll
    for (int ni = 0; ni < 8; ++ni) {
      const int kr = ni * 16 + lo;
      bf16x8 kf = *(const bf16x8*)&kld[kr * 64 + (((hi + ks * 4) ^ (kr & 7)) << 3)];
      s2[0][ni] = __builtin_amdgcn_mfma_f32_16x16x32_bf16(kf, qf[0][ks], s2[0][ni], 0, 0, 0);
      s2[1][ni] = __builtin_amdgcn_mfma_f32_16x16x32_bf16(kf, qf[1][ks], s2[1][ni], 0, 0, 0);
    }
  __builtin_amdgcn_s_setprio(0);

  // ---- softmax + pack + butterfly exchange (round-11 verbatim) ----
  unsigned setA[2][4][2], setB[2][4][2];
#pragma unroll
  for (int cg = 0; cg < 2; ++cg) {
    float mx = s2[cg][0][0];
#pragma unroll
    for (int ni = 0; ni < 8; ++ni)
#pragma unroll
      for (int j = 0; j < 4; ++j) mx = fmaxf(mx, s2[cg][ni][j]);
    mx = fmaxf(mx, __shfl_xor(mx, 16, 64));
    mx = fmaxf(mx, __shfl_xor(mx, 32, 64));
    float sum = 0.f;
#pragma unroll
    for (int ni = 0; ni < 8; ++ni)
#pragma unroll
      for (int j = 0; j < 4; ++j) {
        float e = exp2f((s2[cg][ni][j] - mx) * 1.44269504f);
        s2[cg][ni][j] = e;
        sum += e;
      }
    sum += __shfl_xor(sum, 16, 64);
    sum += __shfl_xor(sum, 32, 64);
    const float r = 1.f / sum;

    unsigned pkE[4][2], pkO[4][2];
#pragma unroll
    for (int o = 0; o < 4; ++o) {
      pkE[o][0] = cvtpk(s2[cg][2 * o][0] * r, s2[cg][2 * o][1] * r);
      pkE[o][1] = cvtpk(s2[cg][2 * o][2] * r, s2[cg][2 * o][3] * r);
      pkO[o][0] = cvtpk(s2[cg][2 * o + 1][0] * r, s2[cg][2 * o + 1][1] * r);
      pkO[o][1] = cvtpk(s2[cg][2 * o + 1][2] * r, s2[cg][2 * o + 1][3] * r);
    }
    // round 1 (xor32): h0,h1 send pkO (keep pkE); h2,h3 send pkE (keep pkO)
    const bool lowHi = (hi < 2);
    unsigned keepR[4][2], gotR[4][2];
#pragma unroll
    for (int o = 0; o < 4; ++o)
#pragma unroll
      for (int e = 0; e < 2; ++e) {
        unsigned snd = lowHi ? pkO[o][e] : pkE[o][e];
        keepR[o][e] = lowHi ? pkE[o][e] : pkO[o][e];
        gotR[o][e] = __shfl_xor(snd, 32, 64);
      }
    // round 2 (xor16): h0,h3 send gotR ; h1,h2 send keepR
    const bool fwdGot = (hi == 0) || (hi == 3);
    unsigned recv2[4][2];
#pragma unroll
    for (int o = 0; o < 4; ++o)
#pragma unroll
      for (int e = 0; e < 2; ++e) {
        unsigned snd = fwdGot ? gotR[o][e] : keepR[o][e];
        recv2[o][e] = __shfl_xor(snd, 16, 64);
      }
    //   setA (lower class): h0 keepR, h1 recv2, h2 gotR, h3 recv2
    //   setB (upper class): h0 recv2, h1 gotR, h2 recv2, h3 keepR
#pragma unroll
    for (int o = 0; o < 4; ++o)
#pragma unroll
      for (int e = 0; e < 2; ++e) {
        setA[cg][o][e] = (hi & 1) ? recv2[o][e] : (hi == 0 ? keepR[o][e] : gotR[o][e]);
        setB[cg][o][e] = (hi & 1) ? (hi == 1 ? gotR[o][e] : keepR[o][e]) : recv2[o][e];
      }
  }

  // ---- PV (round-11 verbatim) ----
  f32x4 o2[2][4];
#pragma unroll
  for (int cg = 0; cg < 2; ++cg)
#pragma unroll
    for (int ni = 0; ni < 4; ++ni) o2[cg][ni] = f32x4{0.f, 0.f, 0.f, 0.f};
  __builtin_amdgcn_s_setprio(1);
#pragma unroll
  for (int ks = 0; ks < 4; ++ks) {
    const int cch = hi + ks * 4;
    bf16x8 pa[2];
#pragma unroll
    for (int cg = 0; cg < 2; ++cg) {
      u32x4 t;
      t[0] = setA[cg][ks][0]; t[1] = setA[cg][ks][1];
      t[2] = setB[cg][ks][0]; t[3] = setB[cg][ks][1];
      pa[cg] = __builtin_bit_cast(bf16x8, t);
    }
#pragma unroll
    for (int ni = 0; ni < 4; ++ni) {
      const int vr = ni * 16 + lo;
      const int cs = (cch & 8) | ((cch & 7) ^ (vr & 7));
      bf16x8 vf = *(const bf16x8*)&vt[vr * 128 + cs * 8];
      o2[0][ni] = __builtin_amdgcn_mfma_f32_16x16x32_bf16(pa[0], vf, o2[0][ni], 0, 0, 0);
      o2[1][ni] = __builtin_amdgcn_mfma_f32_16x16x32_bf16(pa[1], vf, o2[1][ni], 0, 0, 0);
    }
  }
  __builtin_amdgcn_s_setprio(0);

  // ---- store (P already normalized); ao stays [token][512] for gemm2 ----
  const int b_ = ct >> 7, w_ = ct & 127;
#pragma unroll
  for (int cg = 0; cg < 2; ++cg)
#pragma unroll
    for (int j = 0; j < 4; ++j) {
      const int q = wid * 32 + cg * 16 + hi * 4 + j;
      const size_t obase = ((size_t)(b_ * 16384 + q * 128 + w_)) * 512 + (size_t)n * 64;
#pragma unroll
      for (int ni = 0; ni < 4; ++ni)
        ao[obase + ni * 16 + lo] = f2b(o2[cg][ni][j]);
    }
}

// ---------------- GEMM (256-tile, f32 row output) -- Wo projection ----------------
// (unchanged for attribution)

template <int KK>
__global__ __launch_bounds__(1024) void gemm256(
    const u16* __restrict__ A, const u16* __restrict__ Bt,
    const float* __restrict__ bias, void* __restrict__ Cv, int N) {
  constexpr int NT = KK / 64;
  __shared__ u16 smem[65536];  // 2 x [A 256x64 | B 256x64] bf16 = 128 KiB
  const int tid = threadIdx.x;
  const int lane = tid & 63, wid = tid >> 6;   // wid 0..15
  const int nTn = N >> 8;
  const int qx = gridDim.x >> 3;
  const int wg = (blockIdx.x & 7) * qx + (blockIdx.x >> 3);
  const long m0 = (long)(wg / nTn) * 256;
  const long n0 = (long)(wg % nTn) * 256;
  const int wr = wid >> 2, wc = wid & 3;       // 4x4 waves, each 64x64 out
  const int hi = lane >> 4, lo = lane & 15;
  const u16* Ab = A + m0 * KK;
  const u16* Bb = Bt + n0 * KK;
  const int srow_ = tid >> 3;  // 0..127: row within a 128-row staging round
  const int schunk = tid & 7;  // 16B chunk within row

  f32x4 acc[4][4];
#pragma unroll
  for (int mi = 0; mi < 4; ++mi)
#pragma unroll
    for (int ni = 0; ni < 4; ++ni) acc[mi][ni] = f32x4{0.f, 0.f, 0.f, 0.f};

  auto stage = [&](int t) {
    u16* base = &smem[(t & 1) * 32768];
    const int kt = t * 64;
#pragma unroll
    for (int j = 0; j < 2; ++j) {
      int row = j * 128 + srow_;
      int colE = (schunk ^ (row & 7)) << 3;  // inverse-swizzled global source
      gload_lds16(Ab + (long)row * KK + kt + colE, &base[(j * 1024 + tid) * 8]);
    }
#pragma unroll
    for (int j = 0; j < 2; ++j) {
      int row = j * 128 + srow_;
      int colE = (schunk ^ (row & 7)) << 3;
      gload_lds16(Bb + (long)row * KK + kt + colE, &base[16384 + (j * 1024 + tid) * 8]);
    }
  };

  stage(0);
#pragma unroll
  for (int t = 0; t < NT; ++t) {
    if (t + 1 < NT) {
      stage(t + 1);
      asm volatile("s_waitcnt vmcnt(4)" ::: "memory");  // batch t done; batch t+1 in flight
    } else {
      asm volatile("s_waitcnt vmcnt(0)" ::: "memory");
    }
    __builtin_amdgcn_sched_barrier(0);
    __builtin_amdgcn_s_barrier();
    const u16* aB = &smem[(t & 1) * 32768];
    const u16* bB = aB + 16384;
#pragma unroll
    for (int ks = 0; ks < 2; ++ks) {
      const int slot = ((hi + ks * 4) ^ (lo & 7)) << 3;  // swizzled k-chunk
      bf16x8 af[4], bfr[4];
#pragma unroll
      for (int mi = 0; mi < 4; ++mi)
        af[mi] = *(const bf16x8*)&aB[(wr * 64 + mi * 16 + lo) * 64 + slot];
#pragma unroll
      for (int ni = 0; ni < 4; ++ni)
        bfr[ni] = *(const bf16x8*)&bB[(wc * 64 + ni * 16 + lo) * 64 + slot];
#pragma unroll
      for (int mi = 0; mi < 4; ++mi)
#pragma unroll
        for (int ni = 0; ni < 4; ++ni)
          acc[mi][ni] = __builtin_amdgcn_mfma_f32_16x16x32_bf16(af[mi], bfr[ni], acc[mi][ni], 0, 0, 0);
    }
    __builtin_amdgcn_sched_barrier(0);
    __builtin_amdgcn_s_barrier();
  }

  float bb[4];
#pragma unroll
  for (int ni = 0; ni < 4; ++ni) bb[ni] = bias[n0 + wc * 64 + ni * 16 + lo];

  float* Cg = (float*)Cv;
#pragma unroll
  for (int mi = 0; mi < 4; ++mi)
#pragma unroll
    for (int ni = 0; ni < 4; ++ni) {
      long cg = n0 + wc * 64 + ni * 16 + lo;
#pragma unroll
      for (int j = 0; j < 4; ++j)
        Cg[(m0 + wr * 64 + mi * 16 + hi * 4 + j) * N + cg] = acc[mi][ni][j] + bb[ni];
    }
}

// ---------------- launch ----------------
// ws: xb2 [192,224 MiB) | weights [224,~226 MiB). No qkv buffer (fused away).
// ao (bf16, 64 MB) lives IN d_out; gemm2 runs in-place (race-free as before).

extern "C" void kernel_launch(void* const* d_in, const int* in_sizes, int n_in,
                              void* d_out, int out_size, void* d_ws, size_t ws_size,
                              hipStream_t stream) {
  (void)in_sizes; (void)n_in; (void)out_size; (void)ws_size;
  const float* x  = (const float*)d_in[0];
  const float* Wq = (const float*)d_in[1];
  const float* bq = (const float*)d_in[2];
  const float* Wk = (const float*)d_in[3];
  const float* bk = (const float*)d_in[4];
  const float* Wv = (const float*)d_in[5];
  const float* bv = (const float*)d_in[6];
  const float* Wo = (const float*)d_in[7];
  const float* bo = (const float*)d_in[8];
  float* out = (float*)d_out;

  char* ws = (char*)d_ws;
  const size_t MiB = (size_t)1 << 20;
  u16* xb2   = (u16*)(ws + 192 * MiB);
  u16* wqkvT = (u16*)(ws + 224 * MiB);
  u16* woT   = wqkvT + 1536 * 256;
  float* bqkv = (float*)(woT + 256 * 512);

  prep_x2<<<2048, 256, 0, stream>>>(x, xb2);
  prep_w<<<512, 256, 0, stream>>>(Wq, Wk, Wv, Wo, bq, bk, bv, wqkvT, woT, bqkv);

  qkv_attn<<<4096, 256, 0, stream>>>(xb2, wqkvT, bqkv, (u16*)out);
  gemm256<512><<<256, 1024, 0, stream>>>((const u16*)out, woT, bo, out, 256);
}

// Round 13
// 200.199 us; speedup vs baseline: 1.1505x; 1.1505x over previous
//
#include <hip/hip_runtime.h>

typedef unsigned short u16;
typedef __attribute__((ext_vector_type(8))) short bf16x8;
typedef __attribute__((ext_vector_type(8))) unsigned short u16x8;
typedef __attribute__((ext_vector_type(4))) unsigned u32x4;
typedef __attribute__((ext_vector_type(4))) float f32x4;

#define DEVI static __device__ __forceinline__

DEVI u16 f2b(float f) {
  unsigned u = __builtin_bit_cast(unsigned, f);
  return (u16)((u + 0x7FFFu + ((u >> 16) & 1u)) >> 16);
}

DEVI unsigned cvtpk(float a, float b) {  // lo16 = bf16(a), hi16 = bf16(b)
  unsigned r;
  asm("v_cvt_pk_bf16_f32 %0, %1, %2" : "=v"(r) : "v"(a), "v"(b));
  return r;
}

DEVI void gload_lds16(const void* g, void* l) {
  __builtin_amdgcn_global_load_lds(
      (const __attribute__((address_space(1))) unsigned int*)g,
      (__attribute__((address_space(3))) unsigned int*)l, 16, 0, 0);
}

// ---------------- prep kernels ----------------

__global__ __launch_bounds__(256) void prep_x(const float* __restrict__ x, u16* __restrict__ xb) {
  const int n8 = 65536 * 256 / 8;
  int i = blockIdx.x * blockDim.x + threadIdx.x;
  for (; i < n8; i += gridDim.x * blockDim.x) {
    const float4* p = (const float4*)x + (size_t)i * 2;
    float4 a = p[0], b = p[1];
    u16x8 r;
    r[0] = f2b(a.x); r[1] = f2b(a.y); r[2] = f2b(a.z); r[3] = f2b(a.w);
    r[4] = f2b(b.x); r[5] = f2b(b.y); r[6] = f2b(b.z); r[7] = f2b(b.w);
    *(u16x8*)(xb + (size_t)i * 8) = r;
  }
}

// wqkvT[1536][256]: row n<512 -> Wq[:,n]*0.125 ; 512..1023 -> Wk ; 1024.. -> Wv
// woT[256][512]: row n -> Wo[:,n] ;  bqkv[1536] = concat(bq*0.125, bk, bv)
__global__ __launch_bounds__(256) void prep_w(
    const float* __restrict__ Wq, const float* __restrict__ Wk,
    const float* __restrict__ Wv, const float* __restrict__ Wo,
    const float* __restrict__ bq, const float* __restrict__ bk, const float* __restrict__ bv,
    u16* __restrict__ wqkvT, u16* __restrict__ woT, float* __restrict__ bqkv) {
  const int NW1 = 1536 * 256, NW2 = 256 * 512;
  const int total = NW1 + NW2 + 1536;
  int i = blockIdx.x * blockDim.x + threadIdx.x;
  for (; i < total; i += gridDim.x * blockDim.x) {
    if (i < NW1) {
      int nn = i >> 8, kk = i & 255;
      float v;
      if (nn < 512)       v = Wq[kk * 512 + nn] * 0.125f;
      else if (nn < 1024) v = Wk[kk * 512 + (nn - 512)];
      else                v = Wv[kk * 512 + (nn - 1024)];
      wqkvT[i] = f2b(v);
    } else if (i < NW1 + NW2) {
      int j = i - NW1;
      int nn = j >> 9, kk = j & 511;
      woT[j] = f2b(Wo[kk * 256 + nn]);
    } else {
      int j = i - NW1 - NW2;
      bqkv[j] = (j < 512) ? bq[j] * 0.125f : (j < 1024 ? bk[j - 512] : bv[j - 1024]);
    }
  }
}

// ---------------- gemm128p: QKV GEMM, M-tile = one (b,w) column ----------------
// 128x128 tile, 256 thr (2x2 waves), BK=64, 32 KiB single-buffer LDS.
// M-tile r <-> token (b, y=r, w): A-rows are 64-KB-strided (xb is L3-resident with
// 12x reuse -> read scatter absorbed); epilogue writes land in exactly 2 panels,
// FULLY CONTIGUOUS 16 KB each. Panels t-major: panel = (b*128+w)*24 + t*8 + h.
// NOTE (rounds 7-9,12): 256²-dbuf / 128²-single / column-M / 128²-dbuf-counted-vmcnt
// all pin at MfmaUtil 21±1% & ~2.4 TB/s — this config is the best of the family.

__global__ __launch_bounds__(256) void gemm128p(
    const u16* __restrict__ A, const u16* __restrict__ Bt,
    const float* __restrict__ bias, u16* __restrict__ Cg) {
  constexpr int KK = 256, NT = 4;
  __shared__ u16 smem[16384];  // 32 KiB: [A 128x64 | B 128x64]
  const int tid = threadIdx.x;
  const int lane = tid & 63, wid = tid >> 6;
  const int nTn = 12;  // 1536/128
  const int qx = gridDim.x >> 3;
  const int wg = (blockIdx.x & 7) * qx + (blockIdx.x >> 3);
  const int ct = wg / nTn;            // column tile: b*128 + w
  const int n0 = (wg % nTn) * 128;
  const int b_ = ct >> 7, w_ = ct & 127;
  const long aoff = ((long)b_ * 16384 + w_) * 256;  // token (b, y=0, w) * 256
  const int wr = wid >> 1, wc = wid & 1;  // 2x2 waves, each 64x64 out
  const int hi = lane >> 4, lo = lane & 15;
  const u16* Bb = Bt + (long)n0 * KK;
  const int srow_ = tid >> 3;  // 0..31: row within a 32-row staging round
  const int schunk = tid & 7;  // 16B chunk within row

  f32x4 acc[4][4];
#pragma unroll
  for (int mi = 0; mi < 4; ++mi)
#pragma unroll
    for (int ni = 0; ni < 4; ++ni) acc[mi][ni] = f32x4{0.f, 0.f, 0.f, 0.f};

#pragma unroll
  for (int t = 0; t < NT; ++t) {
    const int kt = t * 64;
#pragma unroll
    for (int j = 0; j < 4; ++j) {
      int row = j * 32 + srow_;
      int colE = (schunk ^ (row & 7)) << 3;  // inverse-swizzled global source
      gload_lds16(A + aoff + (long)row * 32768 + kt + colE, &smem[(j * 256 + tid) * 8]);
    }
#pragma unroll
    for (int j = 0; j < 4; ++j) {
      int row = j * 32 + srow_;
      int colE = (schunk ^ (row & 7)) << 3;
      gload_lds16(Bb + (long)row * KK + kt + colE, &smem[8192 + (j * 256 + tid) * 8]);
    }
    asm volatile("s_waitcnt vmcnt(0)" ::: "memory");
    __builtin_amdgcn_sched_barrier(0);
    __builtin_amdgcn_s_barrier();
    const u16* aB = smem;
    const u16* bB = smem + 8192;
#pragma unroll
    for (int ks = 0; ks < 2; ++ks) {
      const int slot = ((hi + ks * 4) ^ (lo & 7)) << 3;  // swizzled k-chunk
      bf16x8 af[4], bfr[4];
#pragma unroll
      for (int mi = 0; mi < 4; ++mi)
        af[mi] = *(const bf16x8*)&aB[(wr * 64 + mi * 16 + lo) * 64 + slot];
#pragma unroll
      for (int ni = 0; ni < 4; ++ni)
        bfr[ni] = *(const bf16x8*)&bB[(wc * 64 + ni * 16 + lo) * 64 + slot];
#pragma unroll
      for (int mi = 0; mi < 4; ++mi)
#pragma unroll
        for (int ni = 0; ni < 4; ++ni)
          acc[mi][ni] = __builtin_amdgcn_mfma_f32_16x16x32_bf16(af[mi], bfr[ni], acc[mi][ni], 0, 0, 0);
    }
    __builtin_amdgcn_sched_barrier(0);
    __builtin_amdgcn_s_barrier();
  }

  float bb[4];
#pragma unroll
  for (int ni = 0; ni < 4; ++ni) bb[ni] = bias[n0 + wc * 64 + ni * 16 + lo];

  // epilogue: stage 128x128 bf16 C-tile (32 KiB), then contiguous panel stores.
#pragma unroll
  for (int mi = 0; mi < 4; ++mi)
#pragma unroll
    for (int ni = 0; ni < 4; ++ni) {
#pragma unroll
      for (int j = 0; j < 4; ++j) {
        int row = wr * 64 + mi * 16 + hi * 4 + j;
        int chunk = (wc * 8 + ni * 2 + (lo >> 3)) ^ ((row >> 2) & 7);
        smem[row * 128 + chunk * 8 + (lo & 7)] = f2b(acc[mi][ni][j] + bb[ni]);
      }
    }
  __syncthreads();
  const size_t pbase = (size_t)ct * 24 * 8192;
#pragma unroll
  for (int it = 0; it < 8; ++it) {
    int idx = it * 256 + tid;
    int y = idx >> 4, c = idx & 15;
    int cs = c ^ ((y >> 2) & 7);
    int col = n0 + c * 8;
    int t = col >> 9, h = (col >> 6) & 7, dh = col & 63;
    size_t dst = pbase + (size_t)(t * 8 + h) * 8192 + y * 64 + dh;
    *(u16x8*)(Cg + dst) = *(const u16x8*)&smem[y * 128 + cs * 8];
  }
}

// ---------------- GEMM (256-tile, f32 row output) -- Wo projection ----------------

template <int KK>
__global__ __launch_bounds__(1024) void gemm256(
    const u16* __restrict__ A, const u16* __restrict__ Bt,
    const float* __restrict__ bias, void* __restrict__ Cv, int N) {
  constexpr int NT = KK / 64;
  __shared__ u16 smem[65536];  // 2 x [A 256x64 | B 256x64] bf16 = 128 KiB
  const int tid = threadIdx.x;
  const int lane = tid & 63, wid = tid >> 6;   // wid 0..15
  const int nTn = N >> 8;
  const int qx = gridDim.x >> 3;
  const int wg = (blockIdx.x & 7) * qx + (blockIdx.x >> 3);
  const long m0 = (long)(wg / nTn) * 256;
  const long n0 = (long)(wg % nTn) * 256;
  const int wr = wid >> 2, wc = wid & 3;       // 4x4 waves, each 64x64 out
  const int hi = lane >> 4, lo = lane & 15;
  const u16* Ab = A + m0 * KK;
  const u16* Bb = Bt + n0 * KK;
  const int srow_ = tid >> 3;  // 0..127: row within a 128-row staging round
  const int schunk = tid & 7;  // 16B chunk within row

  f32x4 acc[4][4];
#pragma unroll
  for (int mi = 0; mi < 4; ++mi)
#pragma unroll
    for (int ni = 0; ni < 4; ++ni) acc[mi][ni] = f32x4{0.f, 0.f, 0.f, 0.f};

  auto stage = [&](int t) {
    u16* base = &smem[(t & 1) * 32768];
    const int kt = t * 64;
#pragma unroll
    for (int j = 0; j < 2; ++j) {
      int row = j * 128 + srow_;
      int colE = (schunk ^ (row & 7)) << 3;  // inverse-swizzled global source
      gload_lds16(Ab + (long)row * KK + kt + colE, &base[(j * 1024 + tid) * 8]);
    }
#pragma unroll
    for (int j = 0; j < 2; ++j) {
      int row = j * 128 + srow_;
      int colE = (schunk ^ (row & 7)) << 3;
      gload_lds16(Bb + (long)row * KK + kt + colE, &base[16384 + (j * 1024 + tid) * 8]);
    }
  };

  stage(0);
#pragma unroll
  for (int t = 0; t < NT; ++t) {
    if (t + 1 < NT) {
      stage(t + 1);
      asm volatile("s_waitcnt vmcnt(4)" ::: "memory");  // batch t done; batch t+1 in flight
    } else {
      asm volatile("s_waitcnt vmcnt(0)" ::: "memory");
    }
    __builtin_amdgcn_sched_barrier(0);
    __builtin_amdgcn_s_barrier();
    const u16* aB = &smem[(t & 1) * 32768];
    const u16* bB = aB + 16384;
#pragma unroll
    for (int ks = 0; ks < 2; ++ks) {
      const int slot = ((hi + ks * 4) ^ (lo & 7)) << 3;  // swizzled k-chunk
      bf16x8 af[4], bfr[4];
#pragma unroll
      for (int mi = 0; mi < 4; ++mi)
        af[mi] = *(const bf16x8*)&aB[(wr * 64 + mi * 16 + lo) * 64 + slot];
#pragma unroll
      for (int ni = 0; ni < 4; ++ni)
        bfr[ni] = *(const bf16x8*)&bB[(wc * 64 + ni * 16 + lo) * 64 + slot];
#pragma unroll
      for (int mi = 0; mi < 4; ++mi)
#pragma unroll
        for (int ni = 0; ni < 4; ++ni)
          acc[mi][ni] = __builtin_amdgcn_mfma_f32_16x16x32_bf16(af[mi], bfr[ni], acc[mi][ni], 0, 0, 0);
    }
    __builtin_amdgcn_sched_barrier(0);
    __builtin_amdgcn_s_barrier();
  }

  float bb[4];
#pragma unroll
  for (int ni = 0; ni < 4; ++ni) bb[ni] = bias[n0 + wc * 64 + ni * 16 + lo];

  float* Cg = (float*)Cv;
#pragma unroll
  for (int mi = 0; mi < 4; ++mi)
#pragma unroll
    for (int ni = 0; ni < 4; ++ni) {
      long cg = n0 + wc * 64 + ni * 16 + lo;
#pragma unroll
      for (int j = 0; j < 4; ++j)
        Cg[(m0 + wr * 64 + mi * 16 + hi * 4 + j) * N + cg] = acc[mi][ni][j] + bb[ni];
    }
}

// ---------------- axial attention v5: t-major panels + swapped QK^T + in-reg P ----------------

__global__ __launch_bounds__(256, 5) void attn_axial(const u16* __restrict__ qkv,
                                                     u16* __restrict__ ao) {
  __shared__ u16 smem[16384];    // 32 KB
  u16* kld = smem;               // [128][64]  chunk^(row&7) swizzled
  u16* vt  = smem + 8192;        // [64 d][128 yp] chunk-swizzled

  const int g = blockIdx.x;
  const int n = g & 7, w = (g >> 3) & 127, b = g >> 10;
  const int tid = threadIdx.x, lane = tid & 63, wid = tid >> 6;
  const size_t pb = (size_t)(b * 128 + w) * 24 * 8192;
  const u16* Qp = qkv + pb + (size_t)n * 8192;
  const u16* Kp = qkv + pb + (size_t)(8 + n) * 8192;
  const u16* Vp = qkv + pb + (size_t)(16 + n) * 8192;
  const int hi = lane >> 4, lo = lane & 15;

  // ---- K: global -> LDS (contiguous 1 KB per wave-instr) ----
  {
    const int kr0 = tid >> 3, kc = tid & 7;
#pragma unroll
    for (int i = 0; i < 4; ++i) {
      const int row = i * 32 + kr0;
      const int srcC = (kc ^ (row & 7)) << 3;  // inverse-swizzled source within row
      gload_lds16(Kp + row * 64 + srcC, &kld[(i * 256 + tid) * 8]);
    }
  }

  // ---- V -> regs (row stride 128 B; lines shared across waves) ----
  const int vyp = (tid & 63) * 2;
  const u16* vg = Vp + vyp * 64 + wid * 16;
  u16x8 va0 = *(const u16x8*)vg;
  u16x8 va1 = *(const u16x8*)(vg + 8);
  u16x8 vc0 = *(const u16x8*)(vg + 64);
  u16x8 vc1 = *(const u16x8*)(vg + 72);

  // ---- Q B-frags (direct global, 4 independent loads, full-line consumption) ----
  bf16x8 qf[2][2];
#pragma unroll
  for (int cg = 0; cg < 2; ++cg)
#pragma unroll
    for (int ks = 0; ks < 2; ++ks)
      qf[cg][ks] = *(const bf16x8*)(Qp + (wid * 32 + cg * 16 + lo) * 64 + hi * 8 + ks * 32);

  // ---- V transpose -> vt (verbatim-verified write pattern) ----
  {
    unsigned* vt32 = (unsigned*)vt;
    const int cch = vyp >> 3;          // 16B chunk 0..15
    const int cw = (vyp >> 1) & 3;     // dword within chunk
#pragma unroll
    for (int e = 0; e < 8; ++e) {
      const int d0 = wid * 16 + e, d1 = wid * 16 + 8 + e;
      const int c0s = (cch & 8) | ((cch & 7) ^ (d0 & 7));
      const int c1s = (cch & 8) | ((cch & 7) ^ (d1 & 7));
      vt32[d0 * 64 + c0s * 4 + cw] = (unsigned)va0[e] | ((unsigned)vc0[e] << 16);
      vt32[d1 * 64 + c1s * 4 + cw] = (unsigned)va1[e] | ((unsigned)vc1[e] << 16);
    }
  }

  __syncthreads();  // kld (vmcnt) + vt (lgkm) complete; the ONLY barrier

  // ---- swapped QK^T: s2[cg][ni] = S^T fragments (K from LDS, broadcast) ----
  f32x4 s2[2][8];
#pragma unroll
  for (int cg = 0; cg < 2; ++cg)
#pragma unroll
    for (int ni = 0; ni < 8; ++ni) s2[cg][ni] = f32x4{0.f, 0.f, 0.f, 0.f};
  __builtin_amdgcn_s_setprio(1);
#pragma unroll
  for (int ks = 0; ks < 2; ++ks)
#pragma unroll
    for (int ni = 0; ni < 8; ++ni) {
      const int kr = ni * 16 + lo;
      bf16x8 kf = *(const bf16x8*)&kld[kr * 64 + (((hi + ks * 4) ^ (kr & 7)) << 3)];
      s2[0][ni] = __builtin_amdgcn_mfma_f32_16x16x32_bf16(kf, qf[0][ks], s2[0][ni], 0, 0, 0);
      s2[1][ni] = __builtin_amdgcn_mfma_f32_16x16x32_bf16(kf, qf[1][ks], s2[1][ni], 0, 0, 0);
    }
  __builtin_amdgcn_s_setprio(0);

  // ---- softmax + pack + butterfly exchange (no LDS; proven) ----
  unsigned setA[2][4][2], setB[2][4][2];
#pragma unroll
  for (int cg = 0; cg < 2; ++cg) {
    float mx = s2[cg][0][0];
#pragma unroll
    for (int ni = 0; ni < 8; ++ni)
#pragma unroll
      for (int j = 0; j < 4; ++j) mx = fmaxf(mx, s2[cg][ni][j]);
    mx = fmaxf(mx, __shfl_xor(mx, 16, 64));
    mx = fmaxf(mx, __shfl_xor(mx, 32, 64));
    float sum = 0.f;
#pragma unroll
    for (int ni = 0; ni < 8; ++ni)
#pragma unroll
      for (int j = 0; j < 4; ++j) {
        float e = exp2f((s2[cg][ni][j] - mx) * 1.44269504f);
        s2[cg][ni][j] = e;
        sum += e;
      }
    sum += __shfl_xor(sum, 16, 64);
    sum += __shfl_xor(sum, 32, 64);
    const float r = 1.f / sum;

    unsigned pkE[4][2], pkO[4][2];
#pragma unroll
    for (int o = 0; o < 4; ++o) {
      pkE[o][0] = cvtpk(s2[cg][2 * o][0] * r, s2[cg][2 * o][1] * r);
      pkE[o][1] = cvtpk(s2[cg][2 * o][2] * r, s2[cg][2 * o][3] * r);
      pkO[o][0] = cvtpk(s2[cg][2 * o + 1][0] * r, s2[cg][2 * o + 1][1] * r);
      pkO[o][1] = cvtpk(s2[cg][2 * o + 1][2] * r, s2[cg][2 * o + 1][3] * r);
    }
    // round 1 (xor32): h0,h1 send pkO (keep pkE); h2,h3 send pkE (keep pkO)
    const bool lowHi = (hi < 2);
    unsigned keepR[4][2], gotR[4][2];
#pragma unroll
    for (int o = 0; o < 4; ++o)
#pragma unroll
      for (int e = 0; e < 2; ++e) {
        unsigned snd = lowHi ? pkO[o][e] : pkE[o][e];
        keepR[o][e] = lowHi ? pkE[o][e] : pkO[o][e];
        gotR[o][e] = __shfl_xor(snd, 32, 64);
      }
    // round 2 (xor16): h0,h3 send gotR ; h1,h2 send keepR
    const bool fwdGot = (hi == 0) || (hi == 3);
    unsigned recv2[4][2];
#pragma unroll
    for (int o = 0; o < 4; ++o)
#pragma unroll
      for (int e = 0; e < 2; ++e) {
        unsigned snd = fwdGot ? gotR[o][e] : keepR[o][e];
        recv2[o][e] = __shfl_xor(snd, 16, 64);
      }
    //   setA (lower class): h0 keepR, h1 recv2, h2 gotR, h3 recv2
    //   setB (upper class): h0 recv2, h1 gotR, h2 recv2, h3 keepR
#pragma unroll
    for (int o = 0; o < 4; ++o)
#pragma unroll
      for (int e = 0; e < 2; ++e) {
        setA[cg][o][e] = (hi & 1) ? recv2[o][e] : (hi == 0 ? keepR[o][e] : gotR[o][e]);
        setB[cg][o][e] = (hi & 1) ? (hi == 1 ? gotR[o][e] : keepR[o][e]) : recv2[o][e];
      }
  }

  // ---- PV: O[q][d] = P @ V  (A-frag from registers, B-frag from vt) ----
  f32x4 o2[2][4];
#pragma unroll
  for (int cg = 0; cg < 2; ++cg)
#pragma unroll
    for (int ni = 0; ni < 4; ++ni) o2[cg][ni] = f32x4{0.f, 0.f, 0.f, 0.f};
  __builtin_amdgcn_s_setprio(1);
#pragma unroll
  for (int ks = 0; ks < 4; ++ks) {
    const int cch = hi + ks * 4;
    bf16x8 pa[2];
#pragma unroll
    for (int cg = 0; cg < 2; ++cg) {
      u32x4 t;
      t[0] = setA[cg][ks][0]; t[1] = setA[cg][ks][1];
      t[2] = setB[cg][ks][0]; t[3] = setB[cg][ks][1];
      pa[cg] = __builtin_bit_cast(bf16x8, t);
    }
#pragma unroll
    for (int ni = 0; ni < 4; ++ni) {
      const int vr = ni * 16 + lo;
      const int cs = (cch & 8) | ((cch & 7) ^ (vr & 7));
      bf16x8 vf = *(const bf16x8*)&vt[vr * 128 + cs * 8];
      o2[0][ni] = __builtin_amdgcn_mfma_f32_16x16x32_bf16(pa[0], vf, o2[0][ni], 0, 0, 0);
      o2[1][ni] = __builtin_amdgcn_mfma_f32_16x16x32_bf16(pa[1], vf, o2[1][ni], 0, 0, 0);
    }
  }
  __builtin_amdgcn_s_setprio(0);

  // ---- store (P already normalized); ao stays [token][512] for gemm2 ----
#pragma unroll
  for (int cg = 0; cg < 2; ++cg)
#pragma unroll
    for (int j = 0; j < 4; ++j) {
      const int q = wid * 32 + cg * 16 + hi * 4 + j;
      const size_t obase = ((size_t)(b * 16384 + q * 128 + w)) * 512 + (size_t)n * 64;
#pragma unroll
      for (int ni = 0; ni < 4; ++ni)
        ao[obase + ni * 16 + lo] = f2b(o2[cg][ni][j]);
    }
}

// ---------------- launch ----------------
// ws: qkv panels [0,192MiB) | xb [192,224) | weights [224,~226)
// ao (bf16, 64 MB) lives IN d_out; gemm2 runs in-place (each block reads only its
// own 256 rows as bf16 before overwriting them as f32 -> race-free, deterministic).

extern "C" void kernel_launch(void* const* d_in, const int* in_sizes, int n_in,
                              void* d_out, int out_size, void* d_ws, size_t ws_size,
                              hipStream_t stream) {
  (void)in_sizes; (void)n_in; (void)out_size; (void)ws_size;
  const float* x  = (const float*)d_in[0];
  const float* Wq = (const float*)d_in[1];
  const float* bq = (const float*)d_in[2];
  const float* Wk = (const float*)d_in[3];
  const float* bk = (const float*)d_in[4];
  const float* Wv = (const float*)d_in[5];
  const float* bv = (const float*)d_in[6];
  const float* Wo = (const float*)d_in[7];
  const float* bo = (const float*)d_in[8];
  float* out = (float*)d_out;

  char* ws = (char*)d_ws;
  const size_t MiB = (size_t)1 << 20;
  u16* qkv   = (u16*)ws;
  u16* xb    = (u16*)(ws + 192 * MiB);
  u16* wqkvT = (u16*)(ws + 224 * MiB);
  u16* woT   = wqkvT + 1536 * 256;
  float* bqkv = (float*)(woT + 256 * 512);

  prep_x<<<2048, 256, 0, stream>>>(x, xb);
  prep_w<<<512, 256, 0, stream>>>(Wq, Wk, Wv, Wo, bq, bk, bv, wqkvT, woT, bqkv);

  gemm128p<<<6144, 256, 0, stream>>>(xb, wqkvT, bqkv, qkv);
  attn_axial<<<4096, 256, 0, stream>>>(qkv, (u16*)out);
  gemm256<512><<<256, 1024, 0, stream>>>((const u16*)out, woT, bo, out, 256);
}